// Round 4
// baseline (54.614 us; speedup 1.0000x reference)
//
#include <hip/hip_runtime.h>

#define DIM 384      // LN dim
#define RD  16       // reduced dim
#define PD  128      // pair_dim
#define NCH 128      // n-chunk per block in main kernel
#define LN_EPS 1e-5f

typedef float fx4 __attribute__((ext_vector_type(4)));

// ---------------- Kernel A: LayerNorm + Linear(384->16) for x and y rows ----
__global__ __launch_bounds__(128) void ln_reduce_kernel(
    const float* __restrict__ x, const float* __restrict__ y,
    const float* __restrict__ gamma, const float* __restrict__ beta,
    const float* __restrict__ w_red, const float* __restrict__ b_red,
    float* __restrict__ xr, float* __restrict__ yr, int M)
{
  int row = blockIdx.x;
  const float* src;
  float* dst;
  if (row < M) { src = x + (size_t)row * DIM;       dst = xr + (size_t)row * RD; }
  else         { src = y + (size_t)(row - M) * DIM; dst = yr + (size_t)(row - M) * RD; }

  int t = threadIdx.x;
  float v[3];
#pragma unroll
  for (int k = 0; k < 3; ++k) v[k] = src[t + k * 128];

  __shared__ float red[2];
  __shared__ float nrm[DIM];

  float s = v[0] + v[1] + v[2];
#pragma unroll
  for (int off = 32; off; off >>= 1) s += __shfl_down(s, off);
  int wave = t >> 6, lane = t & 63;
  if (lane == 0) red[wave] = s;
  __syncthreads();
  float mu = (red[0] + red[1]) * (1.0f / DIM);
  __syncthreads();

  float d0 = v[0] - mu, d1 = v[1] - mu, d2 = v[2] - mu;
  float s2 = d0 * d0 + d1 * d1 + d2 * d2;
#pragma unroll
  for (int off = 32; off; off >>= 1) s2 += __shfl_down(s2, off);
  if (lane == 0) red[wave] = s2;
  __syncthreads();
  float var = (red[0] + red[1]) * (1.0f / DIM);
  float rsig = rsqrtf(var + LN_EPS);

#pragma unroll
  for (int k = 0; k < 3; ++k) {
    int d = t + k * 128;
    nrm[d] = (v[k] - mu) * rsig * gamma[d] + beta[d];
  }
  __syncthreads();

  int j  = t >> 3;
  int k0 = t & 7;
  float p = 0.f;
  for (int e = k0; e < DIM; e += 8)
    p += nrm[e] * w_red[e * RD + j];
  p += __shfl_xor(p, 1);
  p += __shfl_xor(p, 2);
  p += __shfl_xor(p, 4);
  if (k0 == 0) dst[j] = p + b_red[j];
}

// ---------------- Kernel A2: Vm_all[m][j][p] = sum_i xr[m,i]*w_out[i*16+j,p]
__global__ __launch_bounds__(256) void vm_kernel(
    const float* __restrict__ xr, const float* __restrict__ w_out,
    float* __restrict__ vm)
{
  int m = blockIdx.x;
  int t = threadIdx.x;
  __shared__ float xm[RD];
  if (t < RD) xm[t] = xr[(size_t)m * RD + t];
  __syncthreads();
  int p  = t & 127;
  int jh = t >> 7;          // 0 or 1
#pragma unroll
  for (int jj = 0; jj < 8; ++jj) {
    int j = jh * 8 + jj;
    float acc = 0.f;
#pragma unroll
    for (int i = 0; i < RD; ++i)
      acc += xm[i] * w_out[(size_t)(i * RD + j) * PD + p];
    vm[(size_t)m * RD * PD + j * PD + p] = acc;
  }
}

// ---------------- Kernel B: block = (m, n-chunk of 128); plain fx4 stores --
// LOCAL=0: w from precomputed vm. LOCAL=1: build Vm in LDS from xr+w_out.
template<int LOCAL>
__global__ __launch_bounds__(256) void opm_kernel(
    const float* __restrict__ vm_or_xr, const float* __restrict__ yr,
    const float* __restrict__ w_out, const float* __restrict__ b_out,
    float* __restrict__ out, int N)
{
  __shared__ float ys[NCH * RD];    // 8 KB
  __shared__ float VmL[RD * PD];    // 8 KB (used by LOCAL)

  int m  = blockIdx.y;
  int n0 = blockIdx.x * NCH;
  int t  = threadIdx.x;

  // stage yr chunk: NCH*RD = 2048 floats = 512 fx4, 2 per thread
  {
    fx4* d = (fx4*)ys;
    const fx4* s4 = (const fx4*)(yr + (size_t)n0 * RD);
    d[t]       = s4[t];
    d[t + 256] = s4[t + 256];
  }

  int p4 = (t & 31) * 4;
  int g  = t >> 5;               // 0..7
  fx4 w[RD];

  if (LOCAL) {
    __shared__ float xm[RD];
    if (t < RD) xm[t] = vm_or_xr[(size_t)m * RD + t];  // vm_or_xr = xr
    __syncthreads();
    int p  = t & 127;
    int jh = t >> 7;
#pragma unroll
    for (int jj = 0; jj < 8; ++jj) {
      int j = jh * 8 + jj;
      float acc = 0.f;
#pragma unroll
      for (int i = 0; i < RD; ++i)
        acc += xm[i] * w_out[(size_t)(i * RD + j) * PD + p];
      VmL[j * PD + p] = acc;
    }
    __syncthreads();
#pragma unroll
    for (int j = 0; j < RD; ++j) w[j] = *(const fx4*)&VmL[j * PD + p4];
  } else {
    const float* vb = vm_or_xr + (size_t)m * RD * PD;  // vm_or_xr = vm
#pragma unroll
    for (int j = 0; j < RD; ++j) w[j] = *(const fx4*)&vb[j * PD + p4];
    __syncthreads();  // ys ready
  }

  fx4 bo = *(const fx4*)&b_out[p4];
  float* obase = out + ((size_t)m * N + n0) * PD + p4;

#pragma unroll 4
  for (int it = 0; it < NCH / 8; ++it) {
    int n = it * 8 + g;
    float yv[RD];
#pragma unroll
    for (int k = 0; k < 4; ++k)
      *(fx4*)&yv[k * 4] = *(const fx4*)&ys[n * RD + k * 4];

    fx4 acc = bo;
#pragma unroll
    for (int j = 0; j < RD; ++j)
      acc += yv[j] * w[j];
    *(fx4*)(obase + (size_t)n * PD) = acc;
  }
}

extern "C" void kernel_launch(void* const* d_in, const int* in_sizes, int n_in,
                              void* d_out, int out_size, void* d_ws, size_t ws_size,
                              hipStream_t stream) {
  const float* x        = (const float*)d_in[0];
  const float* y        = (const float*)d_in[1];
  const float* ln_gamma = (const float*)d_in[2];
  const float* ln_beta  = (const float*)d_in[3];
  const float* w_red    = (const float*)d_in[4];
  const float* b_red    = (const float*)d_in[5];
  const float* w_out    = (const float*)d_in[6];
  const float* b_out    = (const float*)d_in[7];
  float* out = (float*)d_out;

  int M = in_sizes[0] / DIM;   // 512
  int N = in_sizes[1] / DIM;   // 512

  float* xr = (float*)d_ws;                 // M*16
  float* yr = xr + (size_t)M * RD;          // N*16
  float* vm = yr + (size_t)N * RD;          // M*16*128 = 4 MB

  size_t need = ((size_t)M * RD + (size_t)N * RD + (size_t)M * RD * PD) * 4;

  ln_reduce_kernel<<<M + N, 128, 0, stream>>>(x, y, ln_gamma, ln_beta,
                                              w_red, b_red, xr, yr, M);

  dim3 grid(N / NCH, M);
  if (ws_size >= need) {
    vm_kernel<<<M, 256, 0, stream>>>(xr, w_out, vm);
    opm_kernel<0><<<grid, 256, 0, stream>>>(vm, yr, w_out, b_out, out, N);
  } else {
    opm_kernel<1><<<grid, 256, 0, stream>>>(xr, yr, w_out, b_out, out, N);
  }
}